// Round 1
// baseline (302.714 us; speedup 1.0000x reference)
//
#include <hip/hip_runtime.h>
#include <math.h>

#define B_TOTAL 16384
#define T_STEPS 20
#define NGRP    1024            // B_TOTAL/16 batch groups per sensor

typedef __attribute__((ext_vector_type(8))) __bf16 bf16x8;
typedef __attribute__((ext_vector_type(4))) float f32x4;

// ---------------------------------------------------------------------------
// pack top-16-bits of two floats into one u32: low16 = a's, high16 = b's
__device__ __forceinline__ unsigned pack_hi16(unsigned a, unsigned b) {
#if __has_builtin(__builtin_amdgcn_perm)
    // v_perm_b32: bytes 0-3 = src1(a), 4-7 = src0(b); dst = [a.2,a.3,b.2,b.3]
    return __builtin_amdgcn_perm(b, a, 0x07060302u);
#else
    return (a >> 16) | (b & 0xFFFF0000u);
#endif
}

__device__ __forceinline__ __bf16 bf16_bits(unsigned short s) {
    __bf16 r; __builtin_memcpy(&r, &s, 2); return r;
}
// Truncation-based Dekker split (unchanged numerics vs previous version).
__device__ __forceinline__ void split_trunc(float x, __bf16& hi, __bf16& lo) {
    unsigned u = __float_as_uint(x);
    hi = bf16_bits((unsigned short)(u >> 16));
    float l = x - __uint_as_float(u & 0xFFFF0000u);
    lo = bf16_bits((unsigned short)(__float_as_uint(l) >> 16));
}

// Fused LSTM cell activation: pre-activations a = (xi, xf, xg, xo), cell c.
// Algebraically identical to sigmoid/tanh form, but 5 exp + 2 rcp instead of
// 5 exp + 5 rcp (trans-pipe is quarter-rate):
//   c' = [c*(1+A)(1+C) + (C-1)(1+B)] / [(1+A)(1+B)(1+C)]   A=e^-xi B=e^-xf C=e^2xg
//   h  = (E-1) / ((1+D)(1+E))                              D=e^-xo E=e^2c'
// |pre-act| <= ~12 (64 terms * 0.177 + bias) => products <= e^48, finite f32.
__device__ __forceinline__ float lstm_act(f32x4 a, float& c) {
    float eA = __expf(-a[0]);
    float eB = __expf(-a[1]);
    float eC = __expf(2.0f * a[2]);
    float aA = 1.0f + eA, aB = 1.0f + eB, aC = 1.0f + eC;
    float pAC = aA * aC;
    float r1  = __builtin_amdgcn_rcpf(pAC * aB);
    c = fmaf(c, pAC, (eC - 1.0f) * aB) * r1;
    float eD = __expf(-a[3]);
    float eE = __expf(2.0f * c);
    float r2 = __builtin_amdgcn_rcpf((1.0f + eD) * (1.0f + eE));
    return (eE - 1.0f) * r2;
}

// ---------------------------------------------------------------------------
// Fused 5-layer LSTM via bf16 MFMA, hi/lo compensated.
//
// LDS h-buffer layout (changed from R5):
//  * K-slot permutation u(j) = (j>>1) + 4*(j&1): thread (w,quad,e)'s two h
//    values (units w*8+quad, w*8+4+quad) land in ADJACENT slots 2q/2q+1 ->
//    one packed ds_write_b32 each for hi/lo instead of 4 conflicted b16s.
//    Compensated by permuting A-frag column order in LOAD_FRAG / w1_prep.
//  * XOR bank swizzle: e-field ^ 2*chunk (precomputed per thread, free per
//    step) so writes are 2-way-conflict max (free per m136).
__global__ __launch_bounds__(256, 4)
void lstm5_mfma(const float* __restrict__ accel, const float* __restrict__ gyro,
                const float* __restrict__ aWih0, const float* __restrict__ aWihR,
                const float* __restrict__ aWhh,  const float* __restrict__ aBih,
                const float* __restrict__ aBhh,
                const float* __restrict__ gWih0, const float* __restrict__ gWihR,
                const float* __restrict__ gWhh,  const float* __restrict__ gBih,
                const float* __restrict__ gBhh,
                __bf16* __restrict__ Xhi, __bf16* __restrict__ Xlo) {
    const int tid  = threadIdx.x;
    const int w    = tid >> 6;        // wave 0..3
    const int lane = tid & 63;
    const int e    = lane & 15;       // elem (B-frag col / C col)
    const int quad = lane >> 4;       // 0..3
    const int sensor = blockIdx.y;
    const int bbase  = blockIdx.x * 16;

    const float* xin  = sensor ? gyro  : accel;
    const float* Wih0 = sensor ? gWih0 : aWih0;
    const float* WihR = sensor ? gWihR : aWihR;
    const float* Whh  = sensor ? gWhh  : aWhh;
    const float* Bih  = sensor ? gBih  : aBih;
    const float* Bhh  = sensor ? gBhh  : aBhh;

    __shared__ __align__(16) unsigned shi[20 * 256];   // packed bf16 pairs
    __shared__ __align__(16) unsigned slo[20 * 256];
    const __bf16* sh16 = (const __bf16*)shi;
    const __bf16* sl16 = (const __bf16*)slo;

    // write slot (u32 units within a t-slab): chunk w, col e^(2w), pair quad
    const int wr_idx  = w * 64 + ((e * 4) ^ (w << 3)) + quad;
    // read base (bf16-element units): chunk quad, col e^(2*quad), 8 slots
    const int rb_base = quad * 128 + ((e * 8) ^ (quad << 4));

    const int ug0 = w * 8 + quad;        // tile 0 unit
    const int ug1 = w * 8 + 4 + quad;    // tile 1 unit

    const int m_row   = lane & 15;
    const int orow_t0 = (m_row & 3) * 32 + (w * 8 + (m_row >> 2));
    const int orow_t1 = (m_row & 3) * 32 + (w * 8 + 4 + (m_row >> 2));

    bf16x8 wih_h0, wih_l0, wih_h1, wih_l1;
    bf16x8 whh_h0, whh_l0, whh_h1, whh_l1;
    f32x4  bias0v, bias1v;
    float  c0 = 0.f, c1 = 0.f;

// A-frag K columns permuted to match the paired-store B layout:
// slot jj holds W[row][quad*8 + u(jj)], u(jj) = (jj>>1) + 4*(jj&1)
#define LOAD_FRAG(Wsrc, orow, fh, fl)                         \
    {                                                         \
        const float* p_ = (Wsrc) + (orow) * 32 + quad * 8;    \
        _Pragma("unroll")                                     \
        for (int jj = 0; jj < 8; ++jj) {                      \
            __bf16 h_, l_;                                    \
            split_trunc(p_[(jj >> 1) + ((jj & 1) << 2)], h_, l_); \
            (fh)[jj] = h_;  (fl)[jj] = l_;                    \
        }                                                     \
    }

#define LOAD_BIAS(l)                                                        \
    {                                                                       \
        _Pragma("unroll")                                                   \
        for (int r = 0; r < 4; ++r) {                                       \
            bias0v[r] = Bih[(l) * 128 + r * 32 + ug0] + Bhh[(l) * 128 + r * 32 + ug0]; \
            bias1v[r] = Bih[(l) * 128 + r * 32 + ug1] + Bhh[(l) * 128 + r * 32 + ug1]; \
        }                                                                   \
    }

#define ACT_STORE(t)                                                        \
    {                                                                       \
        float h0 = lstm_act(acc0, c0);                                      \
        float h1 = lstm_act(acc1, c1);                                      \
        unsigned b0 = __float_as_uint(h0), b1 = __float_as_uint(h1);        \
        unsigned hp = pack_hi16(b0, b1);                                    \
        float l0 = h0 - __uint_as_float(b0 & 0xFFFF0000u);                  \
        float l1 = h1 - __uint_as_float(b1 & 0xFFFF0000u);                  \
        unsigned lp = pack_hi16(__float_as_uint(l0), __float_as_uint(l1));  \
        __syncthreads();  /* all waves done reading shi/slo[t] */           \
        shi[(t) * 256 + wr_idx] = hp;                                       \
        slo[(t) * 256 + wr_idx] = lp;                                       \
        __syncthreads();  /* writes visible before next step's reads */     \
    }

    // ================= layer 0 (ih is K=3, done in VALU) =================
    {
        LOAD_FRAG(Whh, orow_t0, whh_h0, whh_l0);
        LOAD_FRAG(Whh, orow_t1, whh_h1, whh_l1);
        LOAD_BIAS(0);
        float w0reg[2][4][3];
#pragma unroll
        for (int r = 0; r < 4; ++r)
#pragma unroll
            for (int k = 0; k < 3; ++k) {
                w0reg[0][r][k] = Wih0[(r * 32 + ug0) * 3 + k];
                w0reg[1][r][k] = Wih0[(r * 32 + ug1) * 3 + k];
            }
        const float* xrow = xin + (size_t)(bbase + e) * (T_STEPS * 3);

        for (int t = 0; t < T_STEPS; ++t) {
            float x0 = xrow[t * 3 + 0];
            float x1 = xrow[t * 3 + 1];
            float x2 = xrow[t * 3 + 2];
            f32x4 acc0 = bias0v;
            f32x4 acc1 = bias1v;
#pragma unroll
            for (int r = 0; r < 4; ++r) {
                acc0[r] = fmaf(w0reg[0][r][0], x0,
                          fmaf(w0reg[0][r][1], x1,
                          fmaf(w0reg[0][r][2], x2, acc0[r])));
                acc1[r] = fmaf(w0reg[1][r][0], x0,
                          fmaf(w0reg[1][r][1], x1,
                          fmaf(w0reg[1][r][2], x2, acc1[r])));
            }
            if (t > 0) {
                int rb = (t - 1) * 512 + rb_base;
                bf16x8 bh = *(const bf16x8*)(sh16 + rb);
                bf16x8 bl = *(const bf16x8*)(sl16 + rb);
                acc0 = __builtin_amdgcn_mfma_f32_16x16x32_bf16(whh_h0, bh, acc0, 0, 0, 0);
                acc0 = __builtin_amdgcn_mfma_f32_16x16x32_bf16(whh_h0, bl, acc0, 0, 0, 0);
                acc0 = __builtin_amdgcn_mfma_f32_16x16x32_bf16(whh_l0, bh, acc0, 0, 0, 0);
                acc1 = __builtin_amdgcn_mfma_f32_16x16x32_bf16(whh_h1, bh, acc1, 0, 0, 0);
                acc1 = __builtin_amdgcn_mfma_f32_16x16x32_bf16(whh_h1, bl, acc1, 0, 0, 0);
                acc1 = __builtin_amdgcn_mfma_f32_16x16x32_bf16(whh_l1, bh, acc1, 0, 0, 0);
            }
            ACT_STORE(t);
        }
    }

    // ================= layers 1..4 (both projections via MFMA) ===========
    for (int l = 1; l < 5; ++l) {
        const float* Wi = WihR + (l - 1) * 4096;
        const float* Wh = Whh + l * 4096;
        LOAD_FRAG(Wi, orow_t0, wih_h0, wih_l0);
        LOAD_FRAG(Wi, orow_t1, wih_h1, wih_l1);
        LOAD_FRAG(Wh, orow_t0, whh_h0, whh_l0);
        LOAD_FRAG(Wh, orow_t1, whh_h1, whh_l1);
        LOAD_BIAS(l);
        c0 = 0.f; c1 = 0.f;

        for (int t = 0; t < T_STEPS; ++t) {
            const int rb1 = t * 512 + rb_base;
            bf16x8 bh1 = *(const bf16x8*)(sh16 + rb1);
            bf16x8 bl1 = *(const bf16x8*)(sl16 + rb1);
            f32x4 acc0, acc1;
            // ih: x = h_{l-1}(t); bias rides in as C of first MFMA
            acc0 = __builtin_amdgcn_mfma_f32_16x16x32_bf16(wih_h0, bh1, bias0v, 0, 0, 0);
            acc0 = __builtin_amdgcn_mfma_f32_16x16x32_bf16(wih_h0, bl1, acc0, 0, 0, 0);
            acc0 = __builtin_amdgcn_mfma_f32_16x16x32_bf16(wih_l0, bh1, acc0, 0, 0, 0);
            acc1 = __builtin_amdgcn_mfma_f32_16x16x32_bf16(wih_h1, bh1, bias1v, 0, 0, 0);
            acc1 = __builtin_amdgcn_mfma_f32_16x16x32_bf16(wih_h1, bl1, acc1, 0, 0, 0);
            acc1 = __builtin_amdgcn_mfma_f32_16x16x32_bf16(wih_l1, bh1, acc1, 0, 0, 0);
            if (t > 0) {
                const int rb0 = rb1 - 512;
                bf16x8 bh = *(const bf16x8*)(sh16 + rb0);
                bf16x8 bl = *(const bf16x8*)(sl16 + rb0);
                acc0 = __builtin_amdgcn_mfma_f32_16x16x32_bf16(whh_h0, bh, acc0, 0, 0, 0);
                acc0 = __builtin_amdgcn_mfma_f32_16x16x32_bf16(whh_h0, bl, acc0, 0, 0, 0);
                acc0 = __builtin_amdgcn_mfma_f32_16x16x32_bf16(whh_l0, bh, acc0, 0, 0, 0);
                acc1 = __builtin_amdgcn_mfma_f32_16x16x32_bf16(whh_h1, bh, acc1, 0, 0, 0);
                acc1 = __builtin_amdgcn_mfma_f32_16x16x32_bf16(whh_h1, bl, acc1, 0, 0, 0);
                acc1 = __builtin_amdgcn_mfma_f32_16x16x32_bf16(whh_l1, bh, acc1, 0, 0, 0);
            }
            ACT_STORE(t);
        }
    }
    __syncthreads();

    // ---- epilogue: raw copy of (physical) frag-layout hi/lo to global ----
    {
        size_t base = ((size_t)(sensor * NGRP + blockIdx.x)) * (20 * 512);
        float4* dh = (float4*)(Xhi + base);
        float4* dl = (float4*)(Xlo + base);
        const float4* sh = (const float4*)shi;
        const float4* sl = (const float4*)slo;
        for (int i = tid; i < 1280; i += 256) { dh[i] = sh[i]; dl[i] = sl[i]; }
    }
#undef LOAD_FRAG
#undef LOAD_BIAS
#undef ACT_STORE
}

// ---------------------------------------------------------------------------
// fc1_w [128][1280] -> MFMA A-frag hi/lo arrays: [mt 0..7][ks 0..39][lane][8]
// K columns permuted to match the paired-store layout of X.
__global__ void w1_prep(const float* __restrict__ w1,
                        __bf16* __restrict__ w1ah, __bf16* __restrict__ w1al) {
    int t = blockIdx.x * blockDim.x + threadIdx.x;     // 8*40*64 = 20480
    if (t >= 20480) return;
    int lane = t & 63;
    int ks   = (t >> 6) % 40;
    int mt   = t / (64 * 40);
    int row  = mt * 16 + (lane & 15);
    int col0 = ks * 32 + (lane >> 4) * 8;
    const float* src = w1 + row * 1280 + col0;
#pragma unroll
    for (int j = 0; j < 8; ++j) {
        __bf16 h_, l_;
        split_trunc(src[(j >> 1) + ((j & 1) << 2)], h_, l_);
        w1ah[t * 8 + j] = h_;
        w1al[t * 8 + j] = l_;
    }
}

// ---------------------------------------------------------------------------
// Fused fc1+ReLU+fc2, K-split, 2 batch groups (32 cols) per block:
// W1 frags read once per block for BOTH groups -> L2 traffic 671 -> 335 MB,
// and each A-frag pair feeds 6 MFMAs instead of 3.
__global__ __launch_bounds__(256, 4)
void fc_mfma(const __bf16* __restrict__ Xhi, const __bf16* __restrict__ Xlo,
             const __bf16* __restrict__ w1ah, const __bf16* __restrict__ w1al,
             const float* __restrict__ fc1_b, const float* __restrict__ fc2_w,
             const float* __restrict__ fc2_b, float* __restrict__ out) {
    const int tid  = threadIdx.x;
    const int wv   = tid >> 6;       // ks-quarter
    const int lane = tid & 63;
    const int e    = lane & 15;
    const int quad = lane >> 4;
    const int g0   = blockIdx.x * 2; // first of 2 batch groups

    // match lstm5's XOR bank swizzle on the X read
    const int lnoff = (lane * 8) ^ (quad << 4);

    __shared__ __align__(16) f32x4 sacc[4][8][64];   // 32 KB C-partials
    __shared__ float sred[4][16][5];

    f32x4 acc[2][8];
#pragma unroll
    for (int p = 0; p < 2; ++p)
#pragma unroll
        for (int m = 0; m < 8; ++m) acc[p][m] = (f32x4){0.f, 0.f, 0.f, 0.f};

    for (int kk = 0; kk < 10; ++kk) {
        int ks = wv * 10 + kk;                 // 0..39
        int sensor = ks / 20, t = ks % 20;
        size_t bb0 = ((size_t)(sensor * NGRP + g0)) * (20 * 512) + t * 512 + lnoff;
        size_t bb1 = bb0 + (size_t)(20 * 512);
        bf16x8 bh0 = *(const bf16x8*)(Xhi + bb0);
        bf16x8 bl0 = *(const bf16x8*)(Xlo + bb0);
        bf16x8 bh1 = *(const bf16x8*)(Xhi + bb1);
        bf16x8 bl1 = *(const bf16x8*)(Xlo + bb1);
#pragma unroll
        for (int m = 0; m < 8; ++m) {
            const __bf16* ap = w1ah + ((size_t)((m * 40 + ks) * 64 + lane)) * 8;
            const __bf16* al = w1al + ((size_t)((m * 40 + ks) * 64 + lane)) * 8;
            bf16x8 ah = *(const bf16x8*)ap;
            bf16x8 av = *(const bf16x8*)al;
            acc[0][m] = __builtin_amdgcn_mfma_f32_16x16x32_bf16(ah, bh0, acc[0][m], 0, 0, 0);
            acc[0][m] = __builtin_amdgcn_mfma_f32_16x16x32_bf16(ah, bl0, acc[0][m], 0, 0, 0);
            acc[0][m] = __builtin_amdgcn_mfma_f32_16x16x32_bf16(av, bh0, acc[0][m], 0, 0, 0);
            acc[1][m] = __builtin_amdgcn_mfma_f32_16x16x32_bf16(ah, bh1, acc[1][m], 0, 0, 0);
            acc[1][m] = __builtin_amdgcn_mfma_f32_16x16x32_bf16(ah, bl1, acc[1][m], 0, 0, 0);
            acc[1][m] = __builtin_amdgcn_mfma_f32_16x16x32_bf16(av, bh1, acc[1][m], 0, 0, 0);
        }
    }

    // phase 2 (per group): reduce K-partials through LDS, bias, ReLU, fc2.
#pragma unroll 2
    for (int grp = 0; grp < 2; ++grp) {
#pragma unroll
        for (int m = 0; m < 8; ++m) sacc[wv][m][lane] = acc[grp][m];
        __syncthreads();

        float p[5] = {0.f, 0.f, 0.f, 0.f, 0.f};
#pragma unroll
        for (int mm = 0; mm < 2; ++mm) {
            int mt = wv * 2 + mm;
            f32x4 z = sacc[0][mt][lane];
#pragma unroll
            for (int k = 1; k < 4; ++k) {
                f32x4 zz = sacc[k][mt][lane];
#pragma unroll
                for (int r = 0; r < 4; ++r) z[r] += zz[r];
            }
#pragma unroll
            for (int r = 0; r < 4; ++r) {
                int row = mt * 16 + quad * 4 + r;      // C row = quad*4 + reg
                float v = fmaxf(z[r] + fc1_b[row], 0.f);
#pragma unroll
                for (int n = 0; n < 5; ++n) p[n] = fmaf(v, fc2_w[n * 128 + row], p[n]);
            }
        }
#pragma unroll
        for (int n = 0; n < 5; ++n) {
            p[n] += __shfl_xor(p[n], 16, 64);
            p[n] += __shfl_xor(p[n], 32, 64);
        }
        if (quad == 0) {
#pragma unroll
            for (int n = 0; n < 5; ++n) sred[wv][e][n] = p[n];
        }
        __syncthreads();
        if (tid < 80) {
            int col = tid / 5, n = tid - col * 5;
            out[(size_t)((g0 + grp) * 16 + col) * 5 + n] =
                sred[0][col][n] + sred[1][col][n] + sred[2][col][n] + sred[3][col][n] + fc2_b[n];
        }
        // next grp's sacc overwrite is safe: all sacc reads happened before
        // the sync above; sred(g1) writes happen only after the next sync.
    }
}

// ---------------------------------------------------------------------------
extern "C" void kernel_launch(void* const* d_in, const int* in_sizes, int n_in,
                              void* d_out, int out_size, void* d_ws, size_t ws_size,
                              hipStream_t stream) {
    const float* accel  = (const float*)d_in[0];
    const float* gyro   = (const float*)d_in[1];
    const float* aWih0  = (const float*)d_in[2];
    const float* aWihR  = (const float*)d_in[3];
    const float* aWhh   = (const float*)d_in[4];
    const float* aBih   = (const float*)d_in[5];
    const float* aBhh   = (const float*)d_in[6];
    const float* gWih0  = (const float*)d_in[7];
    const float* gWihR  = (const float*)d_in[8];
    const float* gWhh   = (const float*)d_in[9];
    const float* gBih   = (const float*)d_in[10];
    const float* gBhh   = (const float*)d_in[11];
    const float* fc1_w  = (const float*)d_in[12];
    const float* fc1_b  = (const float*)d_in[13];
    const float* fc2_w  = (const float*)d_in[14];
    const float* fc2_b  = (const float*)d_in[15];
    float* out = (float*)d_out;

    const size_t XN = (size_t)2 * NGRP * 20 * 512;    // 20,971,520 bf16 each
    __bf16* Xhi  = (__bf16*)d_ws;
    __bf16* Xlo  = Xhi + XN;
    __bf16* W1ah = Xlo + XN;                          // 163,840 bf16 each
    __bf16* W1al = W1ah + 163840;

    hipLaunchKernelGGL(w1_prep, dim3(80), dim3(256), 0, stream, fc1_w, W1ah, W1al);

    hipLaunchKernelGGL(lstm5_mfma, dim3(NGRP, 2), dim3(256), 0, stream,
                       accel, gyro, aWih0, aWihR, aWhh, aBih, aBhh,
                       gWih0, gWihR, gWhh, gBih, gBhh, Xhi, Xlo);

    hipLaunchKernelGGL(fc_mfma, dim3(NGRP / 2), dim3(256), 0, stream,
                       Xhi, Xlo, W1ah, W1al, fc1_b, fc2_w, fc2_b, out);
}

// Round 2
// 291.235 us; speedup vs baseline: 1.0394x; 1.0394x over previous
//
#include <hip/hip_runtime.h>
#include <math.h>

#define B_TOTAL 16384
#define T_STEPS 20
#define NGRP    1024            // B_TOTAL/16 batch groups per sensor

typedef __attribute__((ext_vector_type(8))) __bf16 bf16x8;
typedef __attribute__((ext_vector_type(4))) float f32x4;

// ---------------------------------------------------------------------------
__device__ __forceinline__ __bf16 bf16_bits(unsigned short s) {
    __bf16 r; __builtin_memcpy(&r, &s, 2); return r;
}
// Truncation-based Dekker split (unchanged numerics).
__device__ __forceinline__ void split_trunc(float x, __bf16& hi, __bf16& lo) {
    unsigned u = __float_as_uint(x);
    hi = bf16_bits((unsigned short)(u >> 16));
    float l = x - __uint_as_float(u & 0xFFFF0000u);
    lo = bf16_bits((unsigned short)(__float_as_uint(l) >> 16));
}

// Fused LSTM cell activation (5 exp + 2 rcp; algebraically = sigmoid/tanh form):
//   c' = [c*(1+A)(1+C) + (C-1)(1+B)] / [(1+A)(1+B)(1+C)]   A=e^-xi B=e^-xf C=e^2xg
//   h  = (E-1) / ((1+D)(1+E))                              D=e^-xo E=e^2c'
__device__ __forceinline__ float lstm_act(f32x4 a, float& c) {
    float eA = __expf(-a[0]);
    float eB = __expf(-a[1]);
    float eC = __expf(2.0f * a[2]);
    float aA = 1.0f + eA, aB = 1.0f + eB, aC = 1.0f + eC;
    float pAC = aA * aC;
    float r1  = __builtin_amdgcn_rcpf(pAC * aB);
    c = fmaf(c, pAC, (eC - 1.0f) * aB) * r1;
    float eD = __expf(-a[3]);
    float eE = __expf(2.0f * c);
    float r2 = __builtin_amdgcn_rcpf((1.0f + eD) * (1.0f + eE));
    return (eE - 1.0f) * r2;
}

// ---------------------------------------------------------------------------
// Fused 5-layer LSTM via bf16 MFMA, hi/lo compensated.
//
// R2: 8 waves / 512 threads per block, ONE unit-tile per thread.
// Same 40 KiB LDS -> still 4 blocks/CU but 32 waves/CU (100% occupancy)
// instead of 16 (50%). Latency of the per-step serial chain (ds_read ->
// 6-MFMA chain -> trans chain -> 2 barriers) is hidden by 2x resident waves.
//
// LDS h-buffer layout (e-major, natural unit pairs):
//   logical: slab t = [e 0..15][k 0..15] u32; u32 k holds units (2k, 2k+1).
//   physical: k's bits[3:2] XORed with (e>>1)&3 -> both the per-thread b16
//   writes and the b128 B-frag reads are <=2-way bank conflicts (free).
//   B-frag read for lane (quad,e): 4 consecutive u32 = units quad*8..+7 in
//   NATURAL order -> A-fragments use natural column order (no permutation).
__global__ __launch_bounds__(512, 8)
void lstm5_mfma(const float* __restrict__ accel, const float* __restrict__ gyro,
                const float* __restrict__ aWih0, const float* __restrict__ aWihR,
                const float* __restrict__ aWhh,  const float* __restrict__ aBih,
                const float* __restrict__ aBhh,
                const float* __restrict__ gWih0, const float* __restrict__ gWihR,
                const float* __restrict__ gWhh,  const float* __restrict__ gBih,
                const float* __restrict__ gBhh,
                __bf16* __restrict__ Xhi, __bf16* __restrict__ Xlo) {
    const int tid  = threadIdx.x;
    const int w    = tid >> 6;        // wave 0..7
    const int lane = tid & 63;
    const int e    = lane & 15;       // batch col within group
    const int quad = lane >> 4;       // 0..3
    const int sensor = blockIdx.y;
    const int bbase  = blockIdx.x * 16;

    const float* xin  = sensor ? gyro  : accel;
    const float* Wih0 = sensor ? gWih0 : aWih0;
    const float* WihR = sensor ? gWihR : aWihR;
    const float* Whh  = sensor ? gWhh  : aWhh;
    const float* Bih  = sensor ? gBih  : aBih;
    const float* Bhh  = sensor ? gBhh  : aBhh;

    __shared__ __align__(16) __bf16 shi[20 * 512];
    __shared__ __align__(16) __bf16 slo[20 * 512];

    const int ug  = w * 4 + quad;        // this thread's hidden unit (0..31)
    const int swz = (e >> 1) & 3;

    // write index (bf16 units within a t-slab):
    //   P(u32) = e*16 + (k ^ (swz<<2)), k = ug>>1 = w*2 + (quad>>1)
    const int widx = (e * 16 + ((w * 2 + (quad >> 1)) ^ (swz << 2))) * 2 + (quad & 1);
    // read base (bf16 units): 8 bf16 = units quad*8..quad*8+7 for col e
    const int rb_base = e * 32 + ((quad ^ swz) << 3);

    const int m_row = lane & 15;
    const int orow  = (m_row & 3) * 32 + (w * 4 + (m_row >> 2));

    bf16x8 wih_h, wih_l, whh_h, whh_l;
    f32x4  biasv;
    float  c0 = 0.f;

// A-frag natural column order: slot jj holds W[row][quad*8 + jj]
#define LOAD_FRAG(Wsrc, fh, fl)                               \
    {                                                         \
        const float* p_ = (Wsrc) + (orow) * 32 + quad * 8;    \
        _Pragma("unroll")                                     \
        for (int jj = 0; jj < 8; ++jj) {                      \
            __bf16 h_, l_;                                    \
            split_trunc(p_[jj], h_, l_);                      \
            (fh)[jj] = h_;  (fl)[jj] = l_;                    \
        }                                                     \
    }

#define LOAD_BIAS(l)                                                        \
    {                                                                       \
        _Pragma("unroll")                                                   \
        for (int r = 0; r < 4; ++r)                                         \
            biasv[r] = Bih[(l) * 128 + r * 32 + ug] + Bhh[(l) * 128 + r * 32 + ug]; \
    }

#define ACT_STORE(t)                                                        \
    {                                                                       \
        float h0 = lstm_act(acc, c0);                                       \
        __bf16 hh_, ll_;                                                    \
        split_trunc(h0, hh_, ll_);                                          \
        __syncthreads();  /* all waves done reading shi/slo[t] */           \
        shi[(t) * 512 + widx] = hh_;                                        \
        slo[(t) * 512 + widx] = ll_;                                        \
        __syncthreads();  /* writes visible before next step's reads */     \
    }

    // ================= layer 0 (ih is K=3, done in VALU) =================
    {
        LOAD_FRAG(Whh, whh_h, whh_l);
        LOAD_BIAS(0);
        float w0reg[4][3];
#pragma unroll
        for (int r = 0; r < 4; ++r)
#pragma unroll
            for (int k = 0; k < 3; ++k)
                w0reg[r][k] = Wih0[(r * 32 + ug) * 3 + k];
        const float* xrow = xin + (size_t)(bbase + e) * (T_STEPS * 3);

        for (int t = 0; t < T_STEPS; ++t) {
            float x0 = xrow[t * 3 + 0];
            float x1 = xrow[t * 3 + 1];
            float x2 = xrow[t * 3 + 2];
            f32x4 acc = biasv;
#pragma unroll
            for (int r = 0; r < 4; ++r)
                acc[r] = fmaf(w0reg[r][0], x0,
                         fmaf(w0reg[r][1], x1,
                         fmaf(w0reg[r][2], x2, acc[r])));
            if (t > 0) {
                int rb = (t - 1) * 512 + rb_base;
                bf16x8 bh = *(const bf16x8*)&shi[rb];
                bf16x8 bl = *(const bf16x8*)&slo[rb];
                acc = __builtin_amdgcn_mfma_f32_16x16x32_bf16(whh_h, bh, acc, 0, 0, 0);
                acc = __builtin_amdgcn_mfma_f32_16x16x32_bf16(whh_h, bl, acc, 0, 0, 0);
                acc = __builtin_amdgcn_mfma_f32_16x16x32_bf16(whh_l, bh, acc, 0, 0, 0);
            }
            ACT_STORE(t);
        }
    }

    // ================= layers 1..4 (both projections via MFMA) ===========
    for (int l = 1; l < 5; ++l) {
        const float* Wi = WihR + (l - 1) * 4096;
        const float* Wh = Whh + l * 4096;
        LOAD_FRAG(Wi, wih_h, wih_l);
        LOAD_FRAG(Wh, whh_h, whh_l);
        LOAD_BIAS(l);
        c0 = 0.f;

        for (int t = 0; t < T_STEPS; ++t) {
            const int rb1 = t * 512 + rb_base;
            bf16x8 bh1 = *(const bf16x8*)&shi[rb1];
            bf16x8 bl1 = *(const bf16x8*)&slo[rb1];
            // ih: x = h_{l-1}(t); bias rides in as C of first MFMA
            f32x4 acc;
            acc = __builtin_amdgcn_mfma_f32_16x16x32_bf16(wih_h, bh1, biasv, 0, 0, 0);
            acc = __builtin_amdgcn_mfma_f32_16x16x32_bf16(wih_h, bl1, acc, 0, 0, 0);
            acc = __builtin_amdgcn_mfma_f32_16x16x32_bf16(wih_l, bh1, acc, 0, 0, 0);
            if (t > 0) {
                const int rb0 = rb1 - 512;
                bf16x8 bh = *(const bf16x8*)&shi[rb0];
                bf16x8 bl = *(const bf16x8*)&slo[rb0];
                acc = __builtin_amdgcn_mfma_f32_16x16x32_bf16(whh_h, bh, acc, 0, 0, 0);
                acc = __builtin_amdgcn_mfma_f32_16x16x32_bf16(whh_h, bl, acc, 0, 0, 0);
                acc = __builtin_amdgcn_mfma_f32_16x16x32_bf16(whh_l, bh, acc, 0, 0, 0);
            }
            ACT_STORE(t);
        }
    }
    __syncthreads();

    // ---- epilogue: raw copy of (physical) frag-layout hi/lo to global ----
    {
        size_t base = ((size_t)(sensor * NGRP + blockIdx.x)) * (20 * 512);
        float4* dh = (float4*)(Xhi + base);
        float4* dl = (float4*)(Xlo + base);
        const float4* sh = (const float4*)shi;
        const float4* sl = (const float4*)slo;
        for (int i = tid; i < 1280; i += 512) { dh[i] = sh[i]; dl[i] = sl[i]; }
    }
#undef LOAD_FRAG
#undef LOAD_BIAS
#undef ACT_STORE
}

// ---------------------------------------------------------------------------
// fc1_w [128][1280] -> MFMA A-frag hi/lo arrays: [mt 0..7][ks 0..39][lane][8]
// Natural column order (matches natural-unit B layout).
__global__ void w1_prep(const float* __restrict__ w1,
                        __bf16* __restrict__ w1ah, __bf16* __restrict__ w1al) {
    int t = blockIdx.x * blockDim.x + threadIdx.x;     // 8*40*64 = 20480
    if (t >= 20480) return;
    int lane = t & 63;
    int ks   = (t >> 6) % 40;
    int mt   = t / (64 * 40);
    int row  = mt * 16 + (lane & 15);
    int col0 = ks * 32 + (lane >> 4) * 8;
    const float* src = w1 + row * 1280 + col0;
#pragma unroll
    for (int j = 0; j < 8; ++j) {
        __bf16 h_, l_;
        split_trunc(src[j], h_, l_);
        w1ah[t * 8 + j] = h_;
        w1al[t * 8 + j] = l_;
    }
}

// ---------------------------------------------------------------------------
// Fused fc1+ReLU+fc2, K-split: block = 256 thr / 4 waves owns 16 batch cols;
// wave wv handles ks = wv*10 .. wv*10+9 (of 40) for ALL 8 m-tiles; C-partials
// reduced through LDS. (R0 structure; only the X read offset matches the new
// LDS/global layout of lstm5.)
__global__ __launch_bounds__(256, 4)
void fc_mfma(const __bf16* __restrict__ Xhi, const __bf16* __restrict__ Xlo,
             const __bf16* __restrict__ w1ah, const __bf16* __restrict__ w1al,
             const float* __restrict__ fc1_b, const float* __restrict__ fc2_w,
             const float* __restrict__ fc2_b, float* __restrict__ out) {
    const int tid  = threadIdx.x;
    const int wv   = tid >> 6;       // ks-quarter
    const int lane = tid & 63;
    const int e    = lane & 15;
    const int quad = lane >> 4;
    const int g    = blockIdx.x;     // batch group (16 cols)

    // match lstm5's physical layout: units quad*8..+7 for col e
    const int lnoff = e * 32 + ((quad ^ ((e >> 1) & 3)) << 3);

    __shared__ __align__(16) f32x4 sacc[4][8][64];   // 32 KB C-partials
    __shared__ float sred[4][16][5];

    f32x4 acc[8];
#pragma unroll
    for (int m = 0; m < 8; ++m) acc[m] = (f32x4){0.f, 0.f, 0.f, 0.f};

    for (int kk = 0; kk < 10; ++kk) {
        int ks = wv * 10 + kk;                 // 0..39
        int sensor = ks / 20, t = ks % 20;     // col = sensor*640 + t*32 + u
        size_t bb = ((size_t)(sensor * NGRP + g)) * (20 * 512) + t * 512 + lnoff;
        bf16x8 bh = *(const bf16x8*)(Xhi + bb);
        bf16x8 bl = *(const bf16x8*)(Xlo + bb);
#pragma unroll
        for (int m = 0; m < 8; ++m) {
            const __bf16* ap = w1ah + ((size_t)((m * 40 + ks) * 64 + lane)) * 8;
            const __bf16* al = w1al + ((size_t)((m * 40 + ks) * 64 + lane)) * 8;
            bf16x8 ah = *(const bf16x8*)ap;
            bf16x8 av = *(const bf16x8*)al;
            acc[m] = __builtin_amdgcn_mfma_f32_16x16x32_bf16(ah, bh, acc[m], 0, 0, 0);
            acc[m] = __builtin_amdgcn_mfma_f32_16x16x32_bf16(ah, bl, acc[m], 0, 0, 0);
            acc[m] = __builtin_amdgcn_mfma_f32_16x16x32_bf16(av, bh, acc[m], 0, 0, 0);
        }
    }
#pragma unroll
    for (int m = 0; m < 8; ++m) sacc[wv][m][lane] = acc[m];
    __syncthreads();

    // phase 2: wave wv reduces m-tiles {2wv, 2wv+1}: sum K-partials, bias,
    // ReLU, fc2 partial over its rows; butterfly over quad bits.
    float p[5] = {0.f, 0.f, 0.f, 0.f, 0.f};
#pragma unroll
    for (int mm = 0; mm < 2; ++mm) {
        int mt = wv * 2 + mm;
        f32x4 z = sacc[0][mt][lane];
#pragma unroll
        for (int k = 1; k < 4; ++k) {
            f32x4 zz = sacc[k][mt][lane];
#pragma unroll
            for (int r = 0; r < 4; ++r) z[r] += zz[r];
        }
#pragma unroll
        for (int r = 0; r < 4; ++r) {
            int row = mt * 16 + quad * 4 + r;      // C row = quad*4 + reg
            float v = fmaxf(z[r] + fc1_b[row], 0.f);
#pragma unroll
            for (int n = 0; n < 5; ++n) p[n] = fmaf(v, fc2_w[n * 128 + row], p[n]);
        }
    }
#pragma unroll
    for (int n = 0; n < 5; ++n) {
        p[n] += __shfl_xor(p[n], 16, 64);
        p[n] += __shfl_xor(p[n], 32, 64);
    }
    if (quad == 0) {
#pragma unroll
        for (int n = 0; n < 5; ++n) sred[wv][e][n] = p[n];
    }
    __syncthreads();
    if (tid < 80) {
        int col = tid / 5, n = tid - col * 5;
        out[(size_t)(g * 16 + col) * 5 + n] =
            sred[0][col][n] + sred[1][col][n] + sred[2][col][n] + sred[3][col][n] + fc2_b[n];
    }
}

// ---------------------------------------------------------------------------
extern "C" void kernel_launch(void* const* d_in, const int* in_sizes, int n_in,
                              void* d_out, int out_size, void* d_ws, size_t ws_size,
                              hipStream_t stream) {
    const float* accel  = (const float*)d_in[0];
    const float* gyro   = (const float*)d_in[1];
    const float* aWih0  = (const float*)d_in[2];
    const float* aWihR  = (const float*)d_in[3];
    const float* aWhh   = (const float*)d_in[4];
    const float* aBih   = (const float*)d_in[5];
    const float* aBhh   = (const float*)d_in[6];
    const float* gWih0  = (const float*)d_in[7];
    const float* gWihR  = (const float*)d_in[8];
    const float* gWhh   = (const float*)d_in[9];
    const float* gBih   = (const float*)d_in[10];
    const float* gBhh   = (const float*)d_in[11];
    const float* fc1_w  = (const float*)d_in[12];
    const float* fc1_b  = (const float*)d_in[13];
    const float* fc2_w  = (const float*)d_in[14];
    const float* fc2_b  = (const float*)d_in[15];
    float* out = (float*)d_out;

    const size_t XN = (size_t)2 * NGRP * 20 * 512;    // 20,971,520 bf16 each
    __bf16* Xhi  = (__bf16*)d_ws;
    __bf16* Xlo  = Xhi + XN;
    __bf16* W1ah = Xlo + XN;                          // 163,840 bf16 each
    __bf16* W1al = W1ah + 163840;

    hipLaunchKernelGGL(w1_prep, dim3(80), dim3(256), 0, stream, fc1_w, W1ah, W1al);

    hipLaunchKernelGGL(lstm5_mfma, dim3(NGRP, 2), dim3(512), 0, stream,
                       accel, gyro, aWih0, aWihR, aWhh, aBih, aBhh,
                       gWih0, gWihR, gWhh, gBih, gBhh, Xhi, Xlo);

    hipLaunchKernelGGL(fc_mfma, dim3(NGRP), dim3(256), 0, stream,
                       Xhi, Xlo, W1ah, W1al, fc1_b, fc2_w, fc2_b, out);
}